// Round 1
// baseline (181.611 us; speedup 1.0000x reference)
//
#include <hip/hip_runtime.h>

// ComboSumModule: six independent sum-over-axis-1 reductions (f32).
// Shapes (compile-time): (2048,128,64) (2048,32,32) (2048,64,64)
//                        (2048,16,48) (2048,200,32) (2048,8,8)
// Outputs concatenated flat in return order -> out4[u] = result for unit u.
//
// Work unit u = one float4 of output. 126,976 units = 1984 blocks x 64 thr.
// 1-wave blocks so round-robin dispatch interleaves heavy (M=200) and light
// (M=8) regions across CUs (~640KB/CU, near the 642KB average).

template <int M, int N>
__device__ __forceinline__ void col_sum(const float* __restrict__ xp,
                                        float* __restrict__ out,
                                        int local, int out_base4) {
  constexpr int N4 = N / 4;
  static_assert(M % 4 == 0, "M divisible by 4");
  const int b  = local / N4;          // const divisor -> magic-mul
  const int n4 = local - b * N4;
  const float4* __restrict__ p =
      reinterpret_cast<const float4*>(xp) + (size_t)b * (M * N4) + n4;

  float4 a0 = make_float4(0.f, 0.f, 0.f, 0.f);
  float4 a1 = make_float4(0.f, 0.f, 0.f, 0.f);
  float4 a2 = make_float4(0.f, 0.f, 0.f, 0.f);
  float4 a3 = make_float4(0.f, 0.f, 0.f, 0.f);

#pragma unroll 2
  for (int m = 0; m < M; m += 4) {
    float4 v0 = p[(size_t)(m + 0) * N4];
    float4 v1 = p[(size_t)(m + 1) * N4];
    float4 v2 = p[(size_t)(m + 2) * N4];
    float4 v3 = p[(size_t)(m + 3) * N4];
    a0.x += v0.x; a0.y += v0.y; a0.z += v0.z; a0.w += v0.w;
    a1.x += v1.x; a1.y += v1.y; a1.z += v1.z; a1.w += v1.w;
    a2.x += v2.x; a2.y += v2.y; a2.z += v2.z; a2.w += v2.w;
    a3.x += v3.x; a3.y += v3.y; a3.z += v3.z; a3.w += v3.w;
  }

  float4 r;
  r.x = (a0.x + a1.x) + (a2.x + a3.x);
  r.y = (a0.y + a1.y) + (a2.y + a3.y);
  r.z = (a0.z + a1.z) + (a2.z + a3.z);
  r.w = (a0.w + a1.w) + (a2.w + a3.w);
  reinterpret_cast<float4*>(out)[out_base4 + local] = r;
}

// Region boundaries in float4 units (all multiples of 64 -> branch-uniform
// waves, zero divergence):
//   x0 [0,      32768)  M=128 N=64
//   x1 [32768,  49152)  M=32  N=32
//   x2 [49152,  81920)  M=64  N=64
//   x3 [81920, 106496)  M=16  N=48
//   x4 [106496,122880)  M=200 N=32
//   x5 [122880,126976)  M=8   N=8
__global__ __launch_bounds__(64) void ComboSumModule_25314537242674_kernel(
    const float* __restrict__ x0, const float* __restrict__ x1,
    const float* __restrict__ x2, const float* __restrict__ x3,
    const float* __restrict__ x4, const float* __restrict__ x5,
    float* __restrict__ out) {
  const int u = blockIdx.x * 64 + threadIdx.x;
  if (u < 32768) {
    col_sum<128, 64>(x0, out, u, 0);
  } else if (u < 49152) {
    col_sum<32, 32>(x1, out, u - 32768, 32768);
  } else if (u < 81920) {
    col_sum<64, 64>(x2, out, u - 49152, 49152);
  } else if (u < 106496) {
    col_sum<16, 48>(x3, out, u - 81920, 81920);
  } else if (u < 122880) {
    col_sum<200, 32>(x4, out, u - 106496, 106496);
  } else {
    col_sum<8, 8>(x5, out, u - 122880, 122880);
  }
}

extern "C" void kernel_launch(void* const* d_in, const int* in_sizes, int n_in,
                              void* d_out, int out_size, void* d_ws, size_t ws_size,
                              hipStream_t stream) {
  const float* x0 = (const float*)d_in[0];
  const float* x1 = (const float*)d_in[1];
  const float* x2 = (const float*)d_in[2];
  const float* x3 = (const float*)d_in[3];
  const float* x4 = (const float*)d_in[4];
  const float* x5 = (const float*)d_in[5];
  // d_in[6] is the python scalar dim=1; reduction axis is baked in.
  float* out = (float*)d_out;

  // 126,976 float4 output units exactly = 1984 blocks x 64 threads.
  ComboSumModule_25314537242674_kernel<<<1984, 64, 0, stream>>>(
      x0, x1, x2, x3, x4, x5, out);
}